// Round 1
// baseline (336.182 us; speedup 1.0000x reference)
//
#include <hip/hip_runtime.h>
#include <math.h>

// RC timing (Elmore) for 200k nets x 16 pins. One thread per net.
// Key structural fact from setup_inputs(): local pin 0 is the root and
// fa_local[i] < i for i>0, so exact tree passes are:
//   bottom-up subtree sum: for i=15..1: acc[fa]+=acc[i]
//   top-down path sum:     for i=1..15: v[i]=v[fa]+x[i]
// Memory-bound: ~77 MB read + ~230 MB write => ~49 us floor @ 6.3 TB/s.

namespace {
constexpr int NS = 16;       // pins per net
constexpr int BLOCK = 64;    // one wave per block, 64 nets per block
constexpr int ST = 17;       // LDS row stride (+1 pad: odd stride spreads banks)
constexpr float INV_DBU = 1.0f / 2000.0f;  // SCALE_FACTOR=1, DBU=2000
}

// Unpack 4-bit parent index j from packed regs (j must be a compile-time-
// unrolled loop index so the shift folds to a constant).
#define FA(j) ((int)((((j) < 8 ? p0 : p1) >> (((j) & 7) * 4)) & 15u))

__global__ __launch_bounds__(BLOCK) void rc_timing_kernel(
    const float* __restrict__ gx, const float* __restrict__ gy,
    const int* __restrict__ gfa,
    const float* __restrict__ base0, const float* __restrict__ base1,
    const float* __restrict__ base2,
    float* __restrict__ out, int n_pins)
{
  // 4 arrays * 64 rows * 17 * 4B = 17,408 B LDS -> 9 blocks/CU
  __shared__ float sA[BLOCK * ST];  // X  -> pin_cap(P) -> beta(B)
  __shared__ float sB[BLOCK * ST];  // Y  -> load/ldelay acc(L) -> impulse
  __shared__ float sC[BLOCK * ST];  // net caps (persistent across modes)
  __shared__ float sD[BLOCK * ST];  // delay(D)

  const int t = threadIdx.x;
  const int pinbase = blockIdx.x * (BLOCK * NS);
  if (pinbase >= n_pins) return;   // grid sized exactly; defensive only
  const int row = t * ST;

  // Cooperative, fully-coalesced float4 global<->LDS staging.
  auto coopload = [&](const float* __restrict__ g, float* s) {
#pragma unroll
    for (int k = 0; k < 4; ++k) {
      const int f = k * (BLOCK * 4) + t * 4;
      const float4 v = *reinterpret_cast<const float4*>(g + f);
      float* p = s + (f >> 4) * ST + (f & 15);
      p[0] = v.x; p[1] = v.y; p[2] = v.z; p[3] = v.w;
    }
  };
  auto coopstore = [&](const float* s, float* __restrict__ g) {
#pragma unroll
    for (int k = 0; k < 4; ++k) {
      const int f = k * (BLOCK * 4) + t * 4;
      const float* p = s + (f >> 4) * ST + (f & 15);
      *reinterpret_cast<float4*>(g + f) = make_float4(p[0], p[1], p[2], p[3]);
    }
  };

  // ---- parent indices of own net, packed 4 bits each into two regs ----
  unsigned p0, p1;
  {
    const int* f = gfa + pinbase + t * NS;
    const int4 a = *reinterpret_cast<const int4*>(f + 0);
    const int4 b = *reinterpret_cast<const int4*>(f + 4);
    const int4 c = *reinterpret_cast<const int4*>(f + 8);
    const int4 d = *reinterpret_cast<const int4*>(f + 12);
    const int off = pinbase + t * NS;
    p0 = (unsigned)(a.x - off)        | ((unsigned)(a.y - off) << 4)  |
         ((unsigned)(a.z - off) << 8) | ((unsigned)(a.w - off) << 12) |
         ((unsigned)(b.x - off) << 16)| ((unsigned)(b.y - off) << 20) |
         ((unsigned)(b.z - off) << 24)| ((unsigned)(b.w - off) << 28);
    p1 = (unsigned)(c.x - off)        | ((unsigned)(c.y - off) << 4)  |
         ((unsigned)(c.z - off) << 8) | ((unsigned)(c.w - off) << 12) |
         ((unsigned)(d.x - off) << 16)| ((unsigned)(d.y - off) << 20) |
         ((unsigned)(d.z - off) << 24)| ((unsigned)(d.w - off) << 28);
  }

  // ---- phase A: edge lengths -> res (regs) + net caps (LDS) ----
  coopload(gx + pinbase, sA);
  coopload(gy + pinbase, sB);
#pragma unroll
  for (int j = 0; j < NS; ++j) sC[row + j] = 0.0f;
  __syncthreads();  // coop loads complete before own-row reads

  float res[NS];
  res[0] = 0.0f;
#pragma unroll
  for (int i = 1; i < NS; ++i) {
    const int fa = FA(i);
    const float dx = fabsf(sA[row + fa] - sA[row + i]);
    const float dy = fabsf(sB[row + fa] - sB[row + i]);
    const float len = (dx + dy) * INV_DBU;
    const float r = len * 0.1f;  // == res_e; also == 0.5*cap_e (0.2*0.5)
    res[i] = r;
    sC[row + i] += r;
    sC[row + fa] += r;
  }
  __syncthreads();  // own-row X/Y reads done before mode loop overwrites sA

  // ---- 3 modes ----
#pragma unroll 1
  for (int m = 0; m < 3; ++m) {
    const float* bp = (m == 0) ? base0 : ((m == 1) ? base1 : base2);
    coopload(bp + pinbase, sA);
    __syncthreads();

    // pin_cap: P = base + caps
#pragma unroll
    for (int j = 0; j < NS; ++j) sA[row + j] += sC[row + j];
    __syncthreads();
    coopstore(sA, out + (size_t)(0 * 3 + m) * n_pins + pinbase);

    // load: bottom-up subtree sum of P
#pragma unroll
    for (int j = 0; j < NS; ++j) sB[row + j] = sA[row + j];
#pragma unroll
    for (int i = NS - 1; i >= 1; --i) sB[row + FA(i)] += sB[row + i];
    __syncthreads();
    coopstore(sB, out + (size_t)(1 * 3 + m) * n_pins + pinbase);

    // delay: top-down path sum of res*load
    sD[row + 0] = 0.0f;
#pragma unroll
    for (int i = 1; i < NS; ++i)
      sD[row + i] = sD[row + FA(i)] + res[i] * sB[row + i];
    __syncthreads();
    coopstore(sD, out + (size_t)(2 * 3 + m) * n_pins + pinbase);

    // ldelay: bottom-up subtree sum of P*D
#pragma unroll
    for (int j = 0; j < NS; ++j) sB[row + j] = sA[row + j] * sD[row + j];
#pragma unroll
    for (int i = NS - 1; i >= 1; --i) sB[row + FA(i)] += sB[row + i];
    __syncthreads();
    coopstore(sB, out + (size_t)(3 * 3 + m) * n_pins + pinbase);

    // beta: top-down path sum of res*ldelay (overwrites P; P no longer needed)
    sA[row + 0] = 0.0f;
#pragma unroll
    for (int i = 1; i < NS; ++i)
      sA[row + i] = sA[row + FA(i)] + res[i] * sB[row + i];
    __syncthreads();
    coopstore(sA, out + (size_t)(4 * 3 + m) * n_pins + pinbase);

    // impulse = sqrt(max(2*beta - delay^2, 1e-12))
#pragma unroll
    for (int j = 0; j < NS; ++j) {
      const float bb = sA[row + j];
      const float dd = sD[row + j];
      sB[row + j] = sqrtf(fmaxf(2.0f * bb - dd * dd, 1e-12f));
    }
    __syncthreads();
    coopstore(sB, out + (size_t)(5 * 3 + m) * n_pins + pinbase);
    __syncthreads();  // impulse-store reads done before next mode's coopload(sA)
  }
}

extern "C" void kernel_launch(void* const* d_in, const int* in_sizes, int n_in,
                              void* d_out, int out_size, void* d_ws, size_t ws_size,
                              hipStream_t stream) {
  // setup_inputs order:
  // 0 new_x, 1 new_y, 2 net_flat_topo_sort, 3 net_flat_topo_sort_start,
  // 4 pin_fa, 5 flat_pin_to_start, 6 flat_pin_to, 7 flat_pin_from,
  // 8 pin_caps_base, 9 pin_rcaps_base, 10 pin_fcaps_base
  const float* gx = (const float*)d_in[0];
  const float* gy = (const float*)d_in[1];
  const int*   gfa = (const int*)d_in[4];
  const float* b0 = (const float*)d_in[8];
  const float* b1 = (const float*)d_in[9];
  const float* b2 = (const float*)d_in[10];
  float* out = (float*)d_out;

  const int n_pins = in_sizes[0];            // 3,200,000
  const int nets = n_pins / NS;              // 200,000 (divisible by BLOCK)
  const int grid = (nets + BLOCK - 1) / BLOCK;  // 3125
  rc_timing_kernel<<<grid, BLOCK, 0, stream>>>(gx, gy, gfa, b0, b1, b2, out,
                                               n_pins);
}

// Round 2
// 332.888 us; speedup vs baseline: 1.0099x; 1.0099x over previous
//
#include <hip/hip_runtime.h>
#include <math.h>

// RC timing (Elmore) for 200k nets x 16 pins. One thread per net, one wave
// per block. fa_local[i] < i (pin 0 = root), so exact tree passes are:
//   bottom-up subtree sum: for i=15..1: acc[fa] += acc[i]
//   top-down path sum:     for i=1..15: v[i]  = v[fa] + x[i]
// R1 change vs R0: 3 modes interleaved (ILP=3 on the dependent LDS chains),
// LDS 4 arrays -> 3 (one in-place chain array per mode; caps/res/P/delay in
// registers). 13 KB LDS -> 12 blocks/CU resident, x3 chain ILP.

namespace {
constexpr int NS = 16;       // pins per net
constexpr int BLOCK = 64;    // one wave per block, 64 nets per block
constexpr int ST = 17;       // LDS row stride (odd => rows spread over banks)
constexpr float INV_DBU = 1.0f / 2000.0f;  // SCALE_FACTOR=1, DBU=2000
}

// Unpack 4-bit parent index j from packed regs (j is a compile-time-unrolled
// loop index so the shift folds to a constant).
#define FA(j) ((int)((((j) < 8 ? p0 : p1) >> (((j) & 7) * 4)) & 15u))

__global__ __launch_bounds__(BLOCK) void rc_timing_kernel(
    const float* __restrict__ gx, const float* __restrict__ gy,
    const int* __restrict__ gfa,
    const float* __restrict__ base0, const float* __restrict__ base1,
    const float* __restrict__ base2,
    float* __restrict__ out, int n_pins)
{
  // 3 arrays * 64 rows * 17 * 4B = 13,056 B -> 12 blocks/CU
  __shared__ float s0[BLOCK * ST];  // mode 0 chain array
  __shared__ float s1[BLOCK * ST];  // mode 1 chain array
  __shared__ float s2[BLOCK * ST];  // mode 2 chain array

  const int t = threadIdx.x;
  const int pinbase = blockIdx.x * (BLOCK * NS);
  const int row = t * ST;

  // Cooperative, fully-coalesced float4 global<->LDS staging (cross-row).
  auto coopload = [&](const float* __restrict__ g, float* s) {
#pragma unroll
    for (int k = 0; k < 4; ++k) {
      const int f = k * (BLOCK * 4) + t * 4;
      const float4 v = *reinterpret_cast<const float4*>(g + f);
      float* p = s + (f >> 4) * ST + (f & 15);
      p[0] = v.x; p[1] = v.y; p[2] = v.z; p[3] = v.w;
    }
  };
  auto coopstore = [&](const float* s, float* __restrict__ g) {
#pragma unroll
    for (int k = 0; k < 4; ++k) {
      const int f = k * (BLOCK * 4) + t * 4;
      const float* p = s + (f >> 4) * ST + (f & 15);
      *reinterpret_cast<float4*>(g + f) = make_float4(p[0], p[1], p[2], p[3]);
    }
  };

  // ---- parent indices of own net, packed 4 bits each into two regs ----
  unsigned p0, p1;
  {
    const int* f = gfa + pinbase + t * NS;
    const int4 a = *reinterpret_cast<const int4*>(f + 0);
    const int4 b = *reinterpret_cast<const int4*>(f + 4);
    const int4 c4 = *reinterpret_cast<const int4*>(f + 8);
    const int4 d4 = *reinterpret_cast<const int4*>(f + 12);
    const int off = pinbase + t * NS;
    p0 = (unsigned)(a.x - off)         | ((unsigned)(a.y - off) << 4)  |
         ((unsigned)(a.z - off) << 8)  | ((unsigned)(a.w - off) << 12) |
         ((unsigned)(b.x - off) << 16) | ((unsigned)(b.y - off) << 20) |
         ((unsigned)(b.z - off) << 24) | ((unsigned)(b.w - off) << 28);
    p1 = (unsigned)(c4.x - off)        | ((unsigned)(c4.y - off) << 4)  |
         ((unsigned)(c4.z - off) << 8) | ((unsigned)(c4.w - off) << 12) |
         ((unsigned)(d4.x - off) << 16)| ((unsigned)(d4.y - off) << 20) |
         ((unsigned)(d4.z - off) << 24)| ((unsigned)(d4.w - off) << 28);
  }

  // ---- phase A: X in s0, Y in s1, caps chain in s2 ----
  coopload(gx + pinbase, s0);
  coopload(gy + pinbase, s1);
#pragma unroll
  for (int j = 0; j < NS; ++j) s2[row + j] = 0.0f;
  __syncthreads();

  float res[NS];
  res[0] = 0.0f;
#pragma unroll
  for (int i = 1; i < NS; ++i) {
    const int fa = FA(i);
    const float dx = fabsf(s0[row + fa] - s0[row + i]);
    const float dy = fabsf(s1[row + fa] - s1[row + i]);
    const float r = (dx + dy) * (INV_DBU * 0.1f);  // res_e == 0.5*cap_e
    res[i] = r;
    s2[row + i] += r;
    s2[row + fa] += r;
  }
  float c[NS];
#pragma unroll
  for (int j = 0; j < NS; ++j) c[j] = s2[row + j];
  __syncthreads();  // own-row reads done before cooploads overwrite

  // ---- bases for all 3 modes ----
  coopload(base0 + pinbase, s0);
  coopload(base1 + pinbase, s1);
  coopload(base2 + pinbase, s2);
  __syncthreads();

  // ---- pin_cap: P = base + caps (regs + in place) ----
  float P[3][NS];
#pragma unroll
  for (int j = 0; j < NS; ++j) {
    P[0][j] = s0[row + j] + c[j]; s0[row + j] = P[0][j];
    P[1][j] = s1[row + j] + c[j]; s1[row + j] = P[1][j];
    P[2][j] = s2[row + j] + c[j]; s2[row + j] = P[2][j];
  }
  __syncthreads();
  coopstore(s0, out + (size_t)0 * n_pins + pinbase);
  coopstore(s1, out + (size_t)1 * n_pins + pinbase);
  coopstore(s2, out + (size_t)2 * n_pins + pinbase);
  __syncthreads();

  // ---- load: bottom-up subtree sum of P, in place, 3-way ILP ----
#pragma unroll
  for (int i = NS - 1; i >= 1; --i) {
    const int fa = FA(i);
    const float a0 = s0[row + i], a1 = s1[row + i], a2 = s2[row + i];
    s0[row + fa] += a0;
    s1[row + fa] += a1;
    s2[row + fa] += a2;
  }
  __syncthreads();
  coopstore(s0, out + (size_t)3 * n_pins + pinbase);
  coopstore(s1, out + (size_t)4 * n_pins + pinbase);
  coopstore(s2, out + (size_t)5 * n_pins + pinbase);
  __syncthreads();

  // ---- delay: top-down path sum of res*load, in place ----
  s0[row] = 0.0f; s1[row] = 0.0f; s2[row] = 0.0f;
#pragma unroll
  for (int i = 1; i < NS; ++i) {
    const int fa = FA(i);
    s0[row + i] = s0[row + fa] + res[i] * s0[row + i];
    s1[row + i] = s1[row + fa] + res[i] * s1[row + i];
    s2[row + i] = s2[row + fa] + res[i] * s2[row + i];
  }
  __syncthreads();
  coopstore(s0, out + (size_t)6 * n_pins + pinbase);
  coopstore(s1, out + (size_t)7 * n_pins + pinbase);
  coopstore(s2, out + (size_t)8 * n_pins + pinbase);
  float D[3][NS];
#pragma unroll
  for (int j = 0; j < NS; ++j) {
    D[0][j] = s0[row + j]; D[1][j] = s1[row + j]; D[2][j] = s2[row + j];
  }
  __syncthreads();

  // ---- ldelay: bottom-up subtree sum of P*D, in place ----
#pragma unroll
  for (int j = 0; j < NS; ++j) {
    s0[row + j] = P[0][j] * D[0][j];
    s1[row + j] = P[1][j] * D[1][j];
    s2[row + j] = P[2][j] * D[2][j];
  }
#pragma unroll
  for (int i = NS - 1; i >= 1; --i) {
    const int fa = FA(i);
    const float a0 = s0[row + i], a1 = s1[row + i], a2 = s2[row + i];
    s0[row + fa] += a0;
    s1[row + fa] += a1;
    s2[row + fa] += a2;
  }
  __syncthreads();
  coopstore(s0, out + (size_t)9  * n_pins + pinbase);
  coopstore(s1, out + (size_t)10 * n_pins + pinbase);
  coopstore(s2, out + (size_t)11 * n_pins + pinbase);
  __syncthreads();

  // ---- beta: top-down path sum of res*ldelay, in place ----
  s0[row] = 0.0f; s1[row] = 0.0f; s2[row] = 0.0f;
#pragma unroll
  for (int i = 1; i < NS; ++i) {
    const int fa = FA(i);
    s0[row + i] = s0[row + fa] + res[i] * s0[row + i];
    s1[row + i] = s1[row + fa] + res[i] * s1[row + i];
    s2[row + i] = s2[row + fa] + res[i] * s2[row + i];
  }
  __syncthreads();
  coopstore(s0, out + (size_t)12 * n_pins + pinbase);
  coopstore(s1, out + (size_t)13 * n_pins + pinbase);
  coopstore(s2, out + (size_t)14 * n_pins + pinbase);
  __syncthreads();

  // ---- impulse = sqrt(max(2*beta - delay^2, 1e-12)), in place ----
#pragma unroll
  for (int j = 0; j < NS; ++j) {
    s0[row + j] = sqrtf(fmaxf(2.0f * s0[row + j] - D[0][j] * D[0][j], 1e-12f));
    s1[row + j] = sqrtf(fmaxf(2.0f * s1[row + j] - D[1][j] * D[1][j], 1e-12f));
    s2[row + j] = sqrtf(fmaxf(2.0f * s2[row + j] - D[2][j] * D[2][j], 1e-12f));
  }
  __syncthreads();
  coopstore(s0, out + (size_t)15 * n_pins + pinbase);
  coopstore(s1, out + (size_t)16 * n_pins + pinbase);
  coopstore(s2, out + (size_t)17 * n_pins + pinbase);
}

extern "C" void kernel_launch(void* const* d_in, const int* in_sizes, int n_in,
                              void* d_out, int out_size, void* d_ws, size_t ws_size,
                              hipStream_t stream) {
  // setup_inputs order:
  // 0 new_x, 1 new_y, 2 net_flat_topo_sort, 3 net_flat_topo_sort_start,
  // 4 pin_fa, 5 flat_pin_to_start, 6 flat_pin_to, 7 flat_pin_from,
  // 8 pin_caps_base, 9 pin_rcaps_base, 10 pin_fcaps_base
  const float* gx = (const float*)d_in[0];
  const float* gy = (const float*)d_in[1];
  const int*   gfa = (const int*)d_in[4];
  const float* b0 = (const float*)d_in[8];
  const float* b1 = (const float*)d_in[9];
  const float* b2 = (const float*)d_in[10];
  float* out = (float*)d_out;

  const int n_pins = in_sizes[0];               // 3,200,000
  const int nets = n_pins / NS;                 // 200,000
  const int grid = (nets + BLOCK - 1) / BLOCK;  // 3125
  rc_timing_kernel<<<grid, BLOCK, 0, stream>>>(gx, gy, gfa, b0, b1, b2, out,
                                               n_pins);
}